// Round 11
// baseline (370.887 us; speedup 1.0000x reference)
//
#include <hip/hip_runtime.h>
#include <hip/hip_fp8.h>
#include <cstdint>
#include <cstddef>

#define BATCH   8
#define SEQ     1024
#define DIMC    768
#define HEADS   12
#define HDIM    64
#define HIDDEN  3072
#define MROWS   (BATCH * SEQ)
#define L2E     1.4426950408889634f

typedef __attribute__((ext_vector_type(8))) short bf16x8;
typedef __attribute__((ext_vector_type(4))) float f32x4;
typedef __attribute__((ext_vector_type(8))) int   i32x8;

__device__ __forceinline__ unsigned short f2b(float f) {
    union { float f; unsigned int u; } v; v.f = f;
    unsigned int u = v.u;
    return (unsigned short)((u + 0x7FFFu + ((u >> 16) & 1u)) >> 16);   // RNE
}
__device__ __forceinline__ unsigned char f2e4m3(float f) {
    __hip_fp8_e4m3 t(f); return t.__x;
}
__device__ __forceinline__ unsigned int b2u(float f) {
    union { float f; unsigned int u; } v; v.f = f; return v.u;
}
__device__ __forceinline__ float u2f(unsigned int u) {
    union { unsigned int u; float f; } v; v.u = u; return v.f;
}
__device__ __forceinline__ void gl_lds16(const void* g, void* l) {
    __builtin_amdgcn_global_load_lds(
        (const __attribute__((address_space(1))) unsigned int*)g,
        (__attribute__((address_space(3))) unsigned int*)l, 16, 0, 0);
}
__device__ __forceinline__ float gelu_fast(float x) {
    float p = x * x;
    float a = fmaf(p, 0.044715f, 1.0f);
    float w = x * a * -2.302118131f;
    float z = exp2f(w);
    return x * __builtin_amdgcn_rcpf(1.0f + z);
}
// load a K=128 fp8 fragment (32 B) from two swizzled 16B LDS chunks
__device__ __forceinline__ i32x8 ld_frag32(const unsigned char* base, int o0, int o1) {
    uint4 lo = *(const uint4*)(base + o0);
    uint4 hi = *(const uint4*)(base + o1);
    i32x8 r;
    r[0] = lo.x; r[1] = lo.y; r[2] = lo.z; r[3] = lo.w;
    r[4] = hi.x; r[5] = hi.y; r[6] = hi.z; r[7] = hi.w;
    return r;
}

// ---------------------------------------------------------------------------
// Merged weight convert + transpose to fp8 (one dispatch for all 6 weights):
// src fp32 [K][N] -> dst e4m3 [N][K].  Flat grid, 32x32 tiles.
// ---------------------------------------------------------------------------
__global__ __launch_bounds__(256) void tcvt_all(
    const float* __restrict__ s0, const float* __restrict__ s1,
    const float* __restrict__ s2, const float* __restrict__ s3,
    const float* __restrict__ s4, const float* __restrict__ s5,
    unsigned char* __restrict__ d0, unsigned char* __restrict__ d1,
    unsigned char* __restrict__ d2, unsigned char* __restrict__ d3,
    unsigned char* __restrict__ d4, unsigned char* __restrict__ d5) {
    __shared__ float tile[32][33];
    int id = blockIdx.x;
    const float* src; unsigned char* dst;
    int K, N, k0, n0;
    if (id < 2304) {
        int mat = id / 576, rem = id % 576;
        K = 768; N = 768;
        k0 = (rem / 24) * 32; n0 = (rem % 24) * 32;
        src = (mat == 0) ? s0 : (mat == 1) ? s1 : (mat == 2) ? s2 : s3;
        dst = (mat == 0) ? d0 : (mat == 1) ? d1 : (mat == 2) ? d2 : d3;
    } else if (id < 4608) {
        int rem = id - 2304;
        K = 768; N = 3072;
        k0 = (rem / 96) * 32; n0 = (rem % 96) * 32;
        src = s4; dst = d4;
    } else {
        int rem = id - 4608;
        K = 3072; N = 768;
        k0 = (rem / 24) * 32; n0 = (rem % 24) * 32;
        src = s5; dst = d5;
    }
    int tx = threadIdx.x, ty = threadIdx.y;
#pragma unroll
    for (int i = 0; i < 4; i++)
        tile[ty + i * 8][tx] = src[(size_t)(k0 + ty + i * 8) * N + n0 + tx];
    __syncthreads();
#pragma unroll
    for (int i = 0; i < 4; i++)
        dst[(size_t)(n0 + ty + i * 8) * K + k0 + tx] = f2e4m3(tile[tx][ty + i * 8]);
}

// ---------------------------------------------------------------------------
// LayerNorm (optionally fused concat).  h_out is e4m3.
// Vectorized (G13, R10: win): 768 fp32/row = 192 lanes x float4.
// ---------------------------------------------------------------------------
__global__ __launch_bounds__(256) void ln_k(const float* __restrict__ xa,
                                            const float* __restrict__ xb,
                                            const float* __restrict__ g,
                                            const float* __restrict__ bt,
                                            float* __restrict__ x_out,
                                            unsigned char* __restrict__ h_out) {
    int r = blockIdx.x;
    const float* src;
    if (xb) {
        int b = r >> 10, nn = r & 1023;
        src = (nn < 512) ? xa + ((size_t)b * 512 + nn) * DIMC
                         : xb + ((size_t)b * 512 + (nn - 512)) * DIMC;
    } else {
        src = xa + (size_t)r * DIMC;
    }
    int t = threadIdx.x;
    const bool act = (t < 192);
    float4 v = act ? *(const float4*)(src + t * 4)
                   : make_float4(0.f, 0.f, 0.f, 0.f);
    float s  = v.x + v.y + v.z + v.w;
    float s2 = v.x * v.x + v.y * v.y + v.z * v.z + v.w * v.w;
#pragma unroll
    for (int off = 32; off > 0; off >>= 1) {
        s  += __shfl_down(s,  off);
        s2 += __shfl_down(s2, off);
    }
    __shared__ float red[8];
    int wid = t >> 6, lane = t & 63;
    if (lane == 0) { red[wid] = s; red[4 + wid] = s2; }
    __syncthreads();
    s  = red[0] + red[1] + red[2] + red[3];
    s2 = red[4] + red[5] + red[6] + red[7];
    float mu  = s * (1.f / DIMC);
    float var = s2 * (1.f / DIMC) - mu * mu;
    float rstd = rsqrtf(var + 1e-5f);
    if (act) {
        if (x_out) *(float4*)(x_out + (size_t)r * DIMC + t * 4) = v;
        float4 gv = *(const float4*)(g  + t * 4);
        float4 bv = *(const float4*)(bt + t * 4);
        uchar4 o;
        o.x = f2e4m3((v.x - mu) * rstd * gv.x + bv.x);
        o.y = f2e4m3((v.y - mu) * rstd * gv.y + bv.y);
        o.z = f2e4m3((v.z - mu) * rstd * gv.z + bv.z);
        o.w = f2e4m3((v.w - mu) * rstd * gv.w + bv.w);
        *(uchar4*)&h_out[(size_t)r * DIMC + t * 4] = o;
    }
}

// ---------------------------------------------------------------------------
// fp8 MFMA GEMM, TMx128 tile (TM=256/128/64), BK=128, global_load_lds,
// XOR 16B-chunk swizzle.  Inner loop: MX-scaled mfma_scale_f32_16x16x128
// with unit scales (R5: -33 us).
// Round 11: TM=256 for the big-M GEMMs (QKV, W1) -- at MX rates the
// 2-barrier structure is barrier-bound (m233: ~72% stall), so doubling
// MFMA-work-per-barrier (32/wave/K-iter) is the lever.  LDS 48 KB.
// MODE 0: QKV (z selects).  z==0: Q bf16, pre-scaled by 0.125*log2e.
//         z==1: K bf16.  z==2: V written DIRECTLY as e4m3 [b,h][d][n].
// MODE 1/3: out_f = resid + gamma*(acc+bias)
// MODE 2: outc = e4m3(gelu_fast(acc+bias))
// ---------------------------------------------------------------------------
template <int MODE, int TM>
__global__ __launch_bounds__(256) void gemm_k(
    const unsigned char* __restrict__ A,
    const unsigned char* __restrict__ Bt0,
    const unsigned char* __restrict__ Bt1,
    const unsigned char* __restrict__ Bt2,
    const float* __restrict__ bias0,
    const float* __restrict__ bias1,
    const float* __restrict__ bias2,
    const float* __restrict__ resid,
    const float* __restrict__ gamma,
    float* __restrict__ outf,
    unsigned short* __restrict__ outb0,
    unsigned short* __restrict__ outb1,
    unsigned short* __restrict__ outb2,
    unsigned char* __restrict__ outc,
    int K, int ldo) {

    constexpr int AI = TM / 32;            // M-frags per wave (8, 4 or 2)
    const int tid  = threadIdx.x;
    const int wid  = tid >> 6, lane = tid & 63;
    const int quad = lane >> 4, l16 = lane & 15;
    const int m0 = blockIdx.y * TM, n0 = blockIdx.x * 128;
    const int waveM = (wid >> 1) * (AI * 16), waveN = (wid & 1) * 64;

    const unsigned char* Bt = Bt0;
    if (MODE == 0) Bt = (blockIdx.z == 0) ? Bt0 : (blockIdx.z == 1) ? Bt1 : Bt2;

    __shared__ __align__(16) unsigned char As[TM * 128];
    __shared__ __align__(16) unsigned char Bs[128 * 128];

    // A staging: TM*8 chunks (AI per thread); B: 1024 chunks (4 per thread)
    int carow[AI], caoff[AI], cbrow[4], cboff[4];
#pragma unroll
    for (int j = 0; j < AI; j++) {
        int c = j * 256 + tid;
        carow[j] = c >> 3;
        caoff[j] = ((c & 7) ^ (carow[j] & 7)) * 16;
    }
#pragma unroll
    for (int j = 0; j < 4; j++) {
        int c = j * 256 + tid;
        cbrow[j] = c >> 3;
        cboff[j] = ((c & 7) ^ (cbrow[j] & 7)) * 16;
    }
    const int asw = l16 & 7;
    // K=128 fragment: source k-chunks quad*2 and quad*2+1, swizzled position
    const int co0 = ((quad * 2) ^ asw) * 16;
    const int co1 = co0 ^ 16;              // (quad*2+1)^asw == ((quad*2)^asw)^1
    int abase[AI], bbase[4];
#pragma unroll
    for (int i = 0; i < AI; i++)
        abase[i] = (waveM + i * 16 + l16) * 128;
#pragma unroll
    for (int i = 0; i < 4; i++)
        bbase[i] = (waveN + i * 16 + l16) * 128;

    f32x4 acc[AI][4] = {};
    const int SC1 = 0x7F7F7F7F;            // e8m0 127 = 1.0 in every byte

    for (int k0 = 0; k0 < K; k0 += 128) {
#pragma unroll
        for (int j = 0; j < AI; j++)
            gl_lds16(&A[(size_t)(m0 + carow[j]) * K + k0 + caoff[j]],
                     &As[(j * 256 + wid * 64) * 16]);
#pragma unroll
        for (int j = 0; j < 4; j++)
            gl_lds16(&Bt[(size_t)(n0 + cbrow[j]) * K + k0 + cboff[j]],
                     &Bs[(j * 256 + wid * 64) * 16]);
        __syncthreads();

        i32x8 bf[4];
#pragma unroll
        for (int j = 0; j < 4; j++)
            bf[j] = ld_frag32(&Bs[bbase[j]], co0, co1);
#pragma unroll
        for (int i = 0; i < AI; i++) {
            i32x8 af = ld_frag32(&As[abase[i]], co0, co1);
#pragma unroll
            for (int j = 0; j < 4; j++)
                acc[i][j] = __builtin_amdgcn_mfma_scale_f32_16x16x128_f8f6f4(
                    af, bf[j], acc[i][j], 0, 0, 0, SC1, 0, SC1);
        }
        __syncthreads();
    }

    const float* bias = bias0;
    unsigned short* outb = outb0;
    if (MODE == 0) {
        bias = (blockIdx.z == 0) ? bias0 : (blockIdx.z == 1) ? bias1 : bias2;
        outb = (blockIdx.z == 0) ? outb0 : (blockIdx.z == 1) ? outb1 : outb2;
    }
    const float qscale = 0.125f * L2E;
#pragma unroll
    for (int i = 0; i < AI; i++) {
#pragma unroll
        for (int j = 0; j < 4; j++) {
            int n = n0 + waveN + j * 16 + l16;
            if (MODE == 0 && blockIdx.z == 2) {
                // V: fused transpose -> e4m3 [b,h][d][n], packed 4B store
                int hh = n >> 6, d = n & 63;
                float bn = bias[n];
                int mb = m0 + waveM + i * 16 + quad * 4;
                int bb = mb >> 10, nn = mb & 1023;
                unsigned int packed = 0;
#pragma unroll
                for (int r = 0; r < 4; r++)
                    packed |= (unsigned int)f2e4m3(acc[i][j][r] + bn) << (8 * r);
                *(unsigned int*)&outc[(((size_t)bb * HEADS + hh) * HDIM + d) * SEQ + nn]
                    = packed;
                continue;
            }
#pragma unroll
            for (int r = 0; r < 4; r++) {
                int m = m0 + waveM + i * 16 + quad * 4 + r;
                float val = acc[i][j][r];
                if (MODE == 0) {
                    val += bias[n];
                    if (blockIdx.z == 0) val *= qscale;   // fold softmax scale into Q
                    int bb = m >> 10, nn = m & 1023;
                    int hh = n >> 6,  d  = n & 63;
                    outb[(((size_t)bb * HEADS + hh) * SEQ + nn) * HDIM + d] = f2b(val);
                } else if (MODE == 1 || MODE == 3) {
                    val += bias[n];
                    outf[(size_t)m * ldo + n] =
                        resid[(size_t)m * ldo + n] + gamma[n] * val;
                } else {
                    outc[(size_t)m * ldo + n] = f2e4m3(gelu_fast(val + bias[n]));
                }
            }
        }
    }
}

// ---------------------------------------------------------------------------
// Flash attention: 4 waves/(b,h), 16 q-rows/wave, 128-key tiles.
// Structure FROZEN (R4 form + R8 MX-PV, measured 65.5 us): single LDS
// buffer, XCD remap, s_setprio, PV/denominator via MX K=128 fp8.
// R1 dbuf ✗, R2 reg-prefetch ✗, R3 64-tile ✗, R7 8-wave ✗.
// ---------------------------------------------------------------------------
__global__ __launch_bounds__(256) void attn_k(const unsigned short* __restrict__ Q,
                                              const unsigned short* __restrict__ Km,
                                              const unsigned char* __restrict__ Vt,
                                              const float* __restrict__ mask,
                                              unsigned char* __restrict__ O) {
    const int flat = blockIdx.y * 96 + blockIdx.x;
    const int xcd  = flat & 7, slot = flat >> 3;       // slot in [0,192)
    const int h = slot % 12, y = slot / 12;            // y in [0,16)
    const int b = xcd;
    const int bh = b * HEADS + h;
    const int tid = threadIdx.x;
    const int wid = tid >> 6, lane = tid & 63;
    const int quad = lane >> 4, l16 = lane & 15;
    const int qw = y * 64 + wid * 16;

    __shared__ __align__(16) unsigned short Ks[128 * 64];
    __shared__ __align__(16) unsigned char  Vs[64 * 128];
    __shared__ __align__(16) unsigned char  Ps[4][16 * 136];
    unsigned char* sp = Ps[wid];

    const unsigned short* Qp = Q + ((size_t)bh * SEQ + qw) * HDIM;
    bf16x8 aQ[2];
    aQ[0] = *(const bf16x8*)(Qp + l16 * HDIM + quad * 8);
    aQ[1] = *(const bf16x8*)(Qp + l16 * HDIM + 32 + quad * 8);

    int kql[4], vql[2];
#pragma unroll
    for (int j = 0; j < 4; j++) {
        int ck = (wid * 4 + j) * 64 + lane;
        int key = ck >> 3, ch = ck & 7;
        kql[j] = key * HDIM + ((ch ^ ((key >> 3) & 7)) * 8);
    }
#pragma unroll
    for (int j = 0; j < 2; j++) {
        int cv = j * 256 + wid * 64 + lane;
        int d = cv >> 3, ch = cv & 7;
        vql[j] = d * SEQ + ((ch ^ (d & 7)) * 16);
    }
    const unsigned short* Kb = Km + (size_t)bh * SEQ * HDIM;
    const unsigned char*  Vb = Vt + (size_t)bh * HDIM * SEQ;
    const float* Mbase = mask + (size_t)b * SEQ * SEQ
                       + (size_t)(qw + quad * 4) * SEQ + 8 * l16;

    f32x4 o[4] = {};
    f32x4 osum = {};
    const int SC1 = 0x7F7F7F7F;              // e8m0 unit scales
    i32x8 ONES8;                             // 32 x e4m3(1.0)
#pragma unroll
    for (int j = 0; j < 8; j++) ONES8[j] = 0x38383838;

    for (int key0 = 0; key0 < SEQ; key0 += 128) {
        // ---- mask preload: 8 fp32 per row per lane ----
        float mreg[4][8];
        const float* mb = Mbase + key0;
#pragma unroll
        for (int r = 0; r < 4; r++) {
            float4 u0 = *(const float4*)(mb + r * SEQ);
            float4 u1 = *(const float4*)(mb + r * SEQ + 4);
            mreg[r][0] = u0.x; mreg[r][1] = u0.y; mreg[r][2] = u0.z; mreg[r][3] = u0.w;
            mreg[r][4] = u1.x; mreg[r][5] = u1.y; mreg[r][6] = u1.z; mreg[r][7] = u1.w;
        }
        // ---- stage K (bf16) and V (e4m3) ----
        const unsigned short* Kg = Kb + (size_t)key0 * HDIM;
        const unsigned char*  Vg = Vb + key0;
#pragma unroll
        for (int j = 0; j < 4; j++)
            gl_lds16(Kg + kql[j], &Ks[(wid * 4 + j) * 512]);
#pragma unroll
        for (int j = 0; j < 2; j++)
            gl_lds16(Vg + vql[j], &Vs[(j * 256 + wid * 64) * 16]);
        __syncthreads();

        // ---- S = Q K^T (Q pre-scaled) ----
        f32x4 s[8];
        __builtin_amdgcn_s_setprio(1);
#pragma unroll
        for (int nt = 0; nt < 8; nt++) {
            const unsigned short* kp = &Ks[(8 * l16 + nt) * 64];
            bf16x8 b0 = *(const bf16x8*)&kp[(quad ^ (l16 & 7)) * 8];
            bf16x8 b1 = *(const bf16x8*)&kp[((4 + quad) ^ (l16 & 7)) * 8];
            f32x4 t = {};
            t = __builtin_amdgcn_mfma_f32_16x16x32_bf16(aQ[0], b0, t, 0, 0, 0);
            t = __builtin_amdgcn_mfma_f32_16x16x32_bf16(aQ[1], b1, t, 0, 0, 0);
            s[nt] = t;
        }
        __builtin_amdgcn_s_setprio(0);

        // ---- softmax numerators -> fp8 P in wave-private LDS ----
#pragma unroll
        for (int r = 0; r < 4; r++) {
            float e[8];
#pragma unroll
            for (int nt = 0; nt < 8; nt++)
                e[nt] = exp2f(fmaf(mreg[r][nt], L2E, s[nt][r]));
            unsigned int d0 = __builtin_amdgcn_cvt_pk_fp8_f32(e[0], e[1], 0, false);
            d0 = __builtin_amdgcn_cvt_pk_fp8_f32(e[2], e[3], d0, true);
            unsigned int d1 = __builtin_amdgcn_cvt_pk_fp8_f32(e[4], e[5], 0, false);
            d1 = __builtin_amdgcn_cvt_pk_fp8_f32(e[6], e[7], d1, true);
            int prow = quad * 4 + r;
            uint2 pv; pv.x = d0; pv.y = d1;
            *(uint2*)&sp[prow * 136 + ((l16 ^ (prow & 7)) * 8)] = pv;
        }
        __builtin_amdgcn_wave_barrier();

        // ---- O += P V ; denominator += P * ones (MX fp8 K=128) ----
        i32x8 aP;
        {
            const int sw = l16 & 7;
            union { long l[4]; i32x8 v; } u;
#pragma unroll
            for (int j = 0; j < 4; j++)
                u.l[j] = *(const long*)&sp[l16 * 136 + (((quad * 4 + j) ^ sw) * 8)];
            aP = u.v;
        }
        __builtin_amdgcn_s_setprio(1);
        osum = __builtin_amdgcn_mfma_scale_f32_16x16x128_f8f6f4(
            aP, ONES8, osum, 0, 0, 0, SC1, 0, SC1);
#pragma unroll
        for (int dt = 0; dt < 4; dt++) {
            const unsigned char* vp = &Vs[(dt * 16 + l16) * 128];
            const int c0 = ((quad * 2) ^ (l16 & 7)) * 16;
            i32x8 bv = ld_frag32(vp, c0, c0 ^ 16);
            o[dt] = __builtin_amdgcn_mfma_scale_f32_16x16x128_f8f6f4(
                aP, bv, o[dt], 0, 0, 0, SC1, 0, SC1);
        }
        __builtin_amdgcn_s_setprio(0);
        __syncthreads();
    }

#pragma unroll
    for (int r = 0; r < 4; r++) {
        float inv = 1.0f / osum[r];
#pragma unroll
        for (int dt = 0; dt < 4; dt++)
            O[(size_t)(b * SEQ + qw + quad * 4 + r) * DIMC + h * HDIM + dt * 16 + l16] =
                f2e4m3(o[dt][r] * inv);
    }
}

// ---------------------------------------------------------------------------
extern "C" void kernel_launch(void* const* d_in, const int* in_sizes, int n_in,
                              void* d_out, int out_size, void* d_ws, size_t ws_size,
                              hipStream_t stream) {
    const float* x_pre = (const float*)d_in[0];
    const float* x_post= (const float*)d_in[1];
    const float* mask  = (const float*)d_in[2];
    const float* ln1g  = (const float*)d_in[3];
    const float* ln1b  = (const float*)d_in[4];
    const float* Wq    = (const float*)d_in[5];
    const float* bq    = (const float*)d_in[6];
    const float* Wk    = (const float*)d_in[7];
    const float* bk    = (const float*)d_in[8];
    const float* Wv    = (const float*)d_in[9];
    const float* bv    = (const float*)d_in[10];
    const float* Wo    = (const float*)d_in[11];
    const float* bo    = (const float*)d_in[12];
    const float* ln2g  = (const float*)d_in[13];
    const float* ln2b  = (const float*)d_in[14];
    const float* W1    = (const float*)d_in[15];
    const float* b1    = (const float*)d_in[16];
    const float* W2    = (const float*)d_in[17];
    const float* b2    = (const float*)d_in[18];
    const float* g1    = (const float*)d_in[19];
    const float* g2    = (const float*)d_in[20];
    float* out = (float*)d_out;

    char* p = (char*)d_ws;
    float* xf  = (float*)p;                  p += (size_t)MROWS * DIMC * 4;
    float* x2f = (float*)p;                  p += (size_t)MROWS * DIMC * 4;
    unsigned char* h8  = (unsigned char*)p;  p += (size_t)MROWS * DIMC;
    unsigned char* O8  = (unsigned char*)p;  p += (size_t)MROWS * DIMC;
    unsigned char* G8  = (unsigned char*)p;  p += (size_t)MROWS * HIDDEN;
    unsigned short* Qb = (unsigned short*)p; p += (size_t)MROWS * DIMC * 2;
    unsigned short* Kb = (unsigned short*)p; p += (size_t)MROWS * DIMC * 2;
    unsigned char* V8  = (unsigned char*)p;  p += (size_t)MROWS * DIMC;
    unsigned char* Wq8 = (unsigned char*)p;  p += (size_t)DIMC * DIMC;
    unsigned char* Wk8 = (unsigned char*)p;  p += (size_t)DIMC * DIMC;
    unsigned char* Wv8 = (unsigned char*)p;  p += (size_t)DIMC * DIMC;
    unsigned char* Wo8 = (unsigned char*)p;  p += (size_t)DIMC * DIMC;
    unsigned char* W18 = (unsigned char*)p;  p += (size_t)DIMC * HIDDEN;
    unsigned char* W28 = (unsigned char*)p;  p += (size_t)DIMC * HIDDEN;

    dim3 tb(32, 8);
    tcvt_all<<<6912, tb, 0, stream>>>(Wq, Wk, Wv, Wo, W1, W2,
                                      Wq8, Wk8, Wv8, Wo8, W18, W28);

    ln_k<<<MROWS, 256, 0, stream>>>(x_pre, x_post, ln1g, ln1b, xf, h8);

    gemm_k<0, 256><<<dim3(6, 32, 3), 256, 0, stream>>>(h8, Wq8, Wk8, Wv8,
        bq, bk, bv, nullptr, nullptr, nullptr, Qb, Kb, nullptr, V8, DIMC, DIMC);

    attn_k<<<dim3(96, 16), 256, 0, stream>>>(Qb, Kb, V8, mask, O8);

    gemm_k<1, 64><<<dim3(6, 128), 256, 0, stream>>>(O8, Wo8, nullptr, nullptr,
        bo, nullptr, nullptr, xf, g1, x2f, nullptr, nullptr, nullptr, nullptr, DIMC, DIMC);

    ln_k<<<MROWS, 256, 0, stream>>>(x2f, nullptr, ln2g, ln2b, nullptr, h8);

    gemm_k<2, 256><<<dim3(24, 32), 256, 0, stream>>>(h8, W18, nullptr, nullptr,
        b1, nullptr, nullptr, nullptr, nullptr, nullptr, nullptr, nullptr, nullptr,
        G8, DIMC, HIDDEN);

    gemm_k<3, 64><<<dim3(6, 128), 256, 0, stream>>>(G8, W28, nullptr, nullptr,
        b2, nullptr, nullptr, x2f, g2, out, nullptr, nullptr, nullptr, nullptr,
        HIDDEN, DIMC);

    (void)in_sizes; (void)n_in; (void)out_size; (void)ws_size;
}

// Round 12
// 329.403 us; speedup vs baseline: 1.1259x; 1.1259x over previous
//
#include <hip/hip_runtime.h>
#include <hip/hip_fp8.h>
#include <cstdint>
#include <cstddef>

#define BATCH   8
#define SEQ     1024
#define DIMC    768
#define HEADS   12
#define HDIM    64
#define HIDDEN  3072
#define MROWS   (BATCH * SEQ)
#define L2E     1.4426950408889634f

typedef __attribute__((ext_vector_type(8))) short bf16x8;
typedef __attribute__((ext_vector_type(4))) float f32x4;
typedef __attribute__((ext_vector_type(8))) int   i32x8;

__device__ __forceinline__ unsigned short f2b(float f) {
    union { float f; unsigned int u; } v; v.f = f;
    unsigned int u = v.u;
    return (unsigned short)((u + 0x7FFFu + ((u >> 16) & 1u)) >> 16);   // RNE
}
__device__ __forceinline__ unsigned char f2e4m3(float f) {
    __hip_fp8_e4m3 t(f); return t.__x;
}
__device__ __forceinline__ unsigned int b2u(float f) {
    union { float f; unsigned int u; } v; v.f = f; return v.u;
}
__device__ __forceinline__ float u2f(unsigned int u) {
    union { unsigned int u; float f; } v; v.u = u; return v.f;
}
__device__ __forceinline__ void gl_lds16(const void* g, void* l) {
    __builtin_amdgcn_global_load_lds(
        (const __attribute__((address_space(1))) unsigned int*)g,
        (__attribute__((address_space(3))) unsigned int*)l, 16, 0, 0);
}
__device__ __forceinline__ float gelu_fast(float x) {
    float p = x * x;
    float a = fmaf(p, 0.044715f, 1.0f);
    float w = x * a * -2.302118131f;
    float z = exp2f(w);
    return x * __builtin_amdgcn_rcpf(1.0f + z);
}
// load a K=128 fp8 fragment (32 B) from two swizzled 16B LDS chunks
__device__ __forceinline__ i32x8 ld_frag32(const unsigned char* base, int o0, int o1) {
    uint4 lo = *(const uint4*)(base + o0);
    uint4 hi = *(const uint4*)(base + o1);
    i32x8 r;
    r[0] = lo.x; r[1] = lo.y; r[2] = lo.z; r[3] = lo.w;
    r[4] = hi.x; r[5] = hi.y; r[6] = hi.z; r[7] = hi.w;
    return r;
}

// ---------------------------------------------------------------------------
// Merged weight convert + transpose to fp8 (one dispatch for all 6 weights):
// src fp32 [K][N] -> dst e4m3 [N][K].  Flat grid, 32x32 tiles.
// ---------------------------------------------------------------------------
__global__ __launch_bounds__(256) void tcvt_all(
    const float* __restrict__ s0, const float* __restrict__ s1,
    const float* __restrict__ s2, const float* __restrict__ s3,
    const float* __restrict__ s4, const float* __restrict__ s5,
    unsigned char* __restrict__ d0, unsigned char* __restrict__ d1,
    unsigned char* __restrict__ d2, unsigned char* __restrict__ d3,
    unsigned char* __restrict__ d4, unsigned char* __restrict__ d5) {
    __shared__ float tile[32][33];
    int id = blockIdx.x;
    const float* src; unsigned char* dst;
    int K, N, k0, n0;
    if (id < 2304) {
        int mat = id / 576, rem = id % 576;
        K = 768; N = 768;
        k0 = (rem / 24) * 32; n0 = (rem % 24) * 32;
        src = (mat == 0) ? s0 : (mat == 1) ? s1 : (mat == 2) ? s2 : s3;
        dst = (mat == 0) ? d0 : (mat == 1) ? d1 : (mat == 2) ? d2 : d3;
    } else if (id < 4608) {
        int rem = id - 2304;
        K = 768; N = 3072;
        k0 = (rem / 96) * 32; n0 = (rem % 96) * 32;
        src = s4; dst = d4;
    } else {
        int rem = id - 4608;
        K = 3072; N = 768;
        k0 = (rem / 24) * 32; n0 = (rem % 24) * 32;
        src = s5; dst = d5;
    }
    int tx = threadIdx.x, ty = threadIdx.y;
#pragma unroll
    for (int i = 0; i < 4; i++)
        tile[ty + i * 8][tx] = src[(size_t)(k0 + ty + i * 8) * N + n0 + tx];
    __syncthreads();
#pragma unroll
    for (int i = 0; i < 4; i++)
        dst[(size_t)(n0 + ty + i * 8) * K + k0 + tx] = f2e4m3(tile[tx][ty + i * 8]);
}

// ---------------------------------------------------------------------------
// LayerNorm (optionally fused concat).  h_out is e4m3.
// Vectorized (G13, R10: win): 768 fp32/row = 192 lanes x float4.
// ---------------------------------------------------------------------------
__global__ __launch_bounds__(256) void ln_k(const float* __restrict__ xa,
                                            const float* __restrict__ xb,
                                            const float* __restrict__ g,
                                            const float* __restrict__ bt,
                                            float* __restrict__ x_out,
                                            unsigned char* __restrict__ h_out) {
    int r = blockIdx.x;
    const float* src;
    if (xb) {
        int b = r >> 10, nn = r & 1023;
        src = (nn < 512) ? xa + ((size_t)b * 512 + nn) * DIMC
                         : xb + ((size_t)b * 512 + (nn - 512)) * DIMC;
    } else {
        src = xa + (size_t)r * DIMC;
    }
    int t = threadIdx.x;
    const bool act = (t < 192);
    float4 v = act ? *(const float4*)(src + t * 4)
                   : make_float4(0.f, 0.f, 0.f, 0.f);
    float s  = v.x + v.y + v.z + v.w;
    float s2 = v.x * v.x + v.y * v.y + v.z * v.z + v.w * v.w;
#pragma unroll
    for (int off = 32; off > 0; off >>= 1) {
        s  += __shfl_down(s,  off);
        s2 += __shfl_down(s2, off);
    }
    __shared__ float red[8];
    int wid = t >> 6, lane = t & 63;
    if (lane == 0) { red[wid] = s; red[4 + wid] = s2; }
    __syncthreads();
    s  = red[0] + red[1] + red[2] + red[3];
    s2 = red[4] + red[5] + red[6] + red[7];
    float mu  = s * (1.f / DIMC);
    float var = s2 * (1.f / DIMC) - mu * mu;
    float rstd = rsqrtf(var + 1e-5f);
    if (act) {
        if (x_out) *(float4*)(x_out + (size_t)r * DIMC + t * 4) = v;
        float4 gv = *(const float4*)(g  + t * 4);
        float4 bv = *(const float4*)(bt + t * 4);
        uchar4 o;
        o.x = f2e4m3((v.x - mu) * rstd * gv.x + bv.x);
        o.y = f2e4m3((v.y - mu) * rstd * gv.y + bv.y);
        o.z = f2e4m3((v.z - mu) * rstd * gv.z + bv.z);
        o.w = f2e4m3((v.w - mu) * rstd * gv.w + bv.w);
        *(uchar4*)&h_out[(size_t)r * DIMC + t * 4] = o;
    }
}

// ---------------------------------------------------------------------------
// fp8 MFMA GEMM, TMx128 tile (TM=128 or 64), BK=128, global_load_lds,
// XOR 16B-chunk swizzle.  Inner loop: MX-scaled mfma_scale_f32_16x16x128
// with unit scales (R5: -33 us).  TM=128 is the verified optimum; TM=256
// regressed (R11: occupancy loss, the R1/R7/m132 trade).
// MODE 0: QKV (z selects).  z==0: Q bf16, pre-scaled by 0.125*log2e.
//         z==1: K bf16.  z==2: V written DIRECTLY as e4m3 [b,h][d][n].
// MODE 1/3: out_f = resid + gamma*(acc+bias)
// MODE 2: outc = e4m3(gelu_fast(acc+bias))
// ---------------------------------------------------------------------------
template <int MODE, int TM>
__global__ __launch_bounds__(256) void gemm_k(
    const unsigned char* __restrict__ A,
    const unsigned char* __restrict__ Bt0,
    const unsigned char* __restrict__ Bt1,
    const unsigned char* __restrict__ Bt2,
    const float* __restrict__ bias0,
    const float* __restrict__ bias1,
    const float* __restrict__ bias2,
    const float* __restrict__ resid,
    const float* __restrict__ gamma,
    float* __restrict__ outf,
    unsigned short* __restrict__ outb0,
    unsigned short* __restrict__ outb1,
    unsigned short* __restrict__ outb2,
    unsigned char* __restrict__ outc,
    int K, int ldo) {

    constexpr int AI = TM / 32;            // M-frags per wave (4 or 2)
    const int tid  = threadIdx.x;
    const int wid  = tid >> 6, lane = tid & 63;
    const int quad = lane >> 4, l16 = lane & 15;
    const int m0 = blockIdx.y * TM, n0 = blockIdx.x * 128;
    const int waveM = (wid >> 1) * (AI * 16), waveN = (wid & 1) * 64;

    const unsigned char* Bt = Bt0;
    if (MODE == 0) Bt = (blockIdx.z == 0) ? Bt0 : (blockIdx.z == 1) ? Bt1 : Bt2;

    __shared__ __align__(16) unsigned char As[TM * 128];
    __shared__ __align__(16) unsigned char Bs[128 * 128];

    // A staging: TM*8 chunks (AI per thread); B: 1024 chunks (4 per thread)
    int carow[AI], caoff[AI], cbrow[4], cboff[4];
#pragma unroll
    for (int j = 0; j < AI; j++) {
        int c = j * 256 + tid;
        carow[j] = c >> 3;
        caoff[j] = ((c & 7) ^ (carow[j] & 7)) * 16;
    }
#pragma unroll
    for (int j = 0; j < 4; j++) {
        int c = j * 256 + tid;
        cbrow[j] = c >> 3;
        cboff[j] = ((c & 7) ^ (cbrow[j] & 7)) * 16;
    }
    const int asw = l16 & 7;
    // K=128 fragment: source k-chunks quad*2 and quad*2+1, swizzled position
    const int co0 = ((quad * 2) ^ asw) * 16;
    const int co1 = co0 ^ 16;              // (quad*2+1)^asw == ((quad*2)^asw)^1
    int abase[AI], bbase[4];
#pragma unroll
    for (int i = 0; i < AI; i++)
        abase[i] = (waveM + i * 16 + l16) * 128;
#pragma unroll
    for (int i = 0; i < 4; i++)
        bbase[i] = (waveN + i * 16 + l16) * 128;

    f32x4 acc[AI][4] = {};
    const int SC1 = 0x7F7F7F7F;            // e8m0 127 = 1.0 in every byte

    for (int k0 = 0; k0 < K; k0 += 128) {
#pragma unroll
        for (int j = 0; j < AI; j++)
            gl_lds16(&A[(size_t)(m0 + carow[j]) * K + k0 + caoff[j]],
                     &As[(j * 256 + wid * 64) * 16]);
#pragma unroll
        for (int j = 0; j < 4; j++)
            gl_lds16(&Bt[(size_t)(n0 + cbrow[j]) * K + k0 + cboff[j]],
                     &Bs[(j * 256 + wid * 64) * 16]);
        __syncthreads();

        i32x8 bf[4];
#pragma unroll
        for (int j = 0; j < 4; j++)
            bf[j] = ld_frag32(&Bs[bbase[j]], co0, co1);
#pragma unroll
        for (int i = 0; i < AI; i++) {
            i32x8 af = ld_frag32(&As[abase[i]], co0, co1);
#pragma unroll
            for (int j = 0; j < 4; j++)
                acc[i][j] = __builtin_amdgcn_mfma_scale_f32_16x16x128_f8f6f4(
                    af, bf[j], acc[i][j], 0, 0, 0, SC1, 0, SC1);
        }
        __syncthreads();
    }

    const float* bias = bias0;
    unsigned short* outb = outb0;
    if (MODE == 0) {
        bias = (blockIdx.z == 0) ? bias0 : (blockIdx.z == 1) ? bias1 : bias2;
        outb = (blockIdx.z == 0) ? outb0 : (blockIdx.z == 1) ? outb1 : outb2;
    }
    const float qscale = 0.125f * L2E;
#pragma unroll
    for (int i = 0; i < AI; i++) {
#pragma unroll
        for (int j = 0; j < 4; j++) {
            int n = n0 + waveN + j * 16 + l16;
            if (MODE == 0 && blockIdx.z == 2) {
                // V: fused transpose -> e4m3 [b,h][d][n], packed 4B store
                int hh = n >> 6, d = n & 63;
                float bn = bias[n];
                int mb = m0 + waveM + i * 16 + quad * 4;
                int bb = mb >> 10, nn = mb & 1023;
                unsigned int packed = 0;
#pragma unroll
                for (int r = 0; r < 4; r++)
                    packed |= (unsigned int)f2e4m3(acc[i][j][r] + bn) << (8 * r);
                *(unsigned int*)&outc[(((size_t)bb * HEADS + hh) * HDIM + d) * SEQ + nn]
                    = packed;
                continue;
            }
#pragma unroll
            for (int r = 0; r < 4; r++) {
                int m = m0 + waveM + i * 16 + quad * 4 + r;
                float val = acc[i][j][r];
                if (MODE == 0) {
                    val += bias[n];
                    if (blockIdx.z == 0) val *= qscale;   // fold softmax scale into Q
                    int bb = m >> 10, nn = m & 1023;
                    int hh = n >> 6,  d  = n & 63;
                    outb[(((size_t)bb * HEADS + hh) * SEQ + nn) * HDIM + d] = f2b(val);
                } else if (MODE == 1 || MODE == 3) {
                    val += bias[n];
                    outf[(size_t)m * ldo + n] =
                        resid[(size_t)m * ldo + n] + gamma[n] * val;
                } else {
                    outc[(size_t)m * ldo + n] = f2e4m3(gelu_fast(val + bias[n]));
                }
            }
        }
    }
}

// ---------------------------------------------------------------------------
// Flash attention: 4 waves/(b,h), 16 q-rows/wave, 128-key tiles.
// Structure FROZEN (R4 form + R8 MX-PV, measured 65.5 us): single LDS
// buffer, XCD remap, s_setprio, PV/denominator via MX K=128 fp8.
// R1 dbuf ✗, R2 reg-prefetch ✗, R3 64-tile ✗, R7 8-wave ✗.
// ---------------------------------------------------------------------------
__global__ __launch_bounds__(256) void attn_k(const unsigned short* __restrict__ Q,
                                              const unsigned short* __restrict__ Km,
                                              const unsigned char* __restrict__ Vt,
                                              const float* __restrict__ mask,
                                              unsigned char* __restrict__ O) {
    const int flat = blockIdx.y * 96 + blockIdx.x;
    const int xcd  = flat & 7, slot = flat >> 3;       // slot in [0,192)
    const int h = slot % 12, y = slot / 12;            // y in [0,16)
    const int b = xcd;
    const int bh = b * HEADS + h;
    const int tid = threadIdx.x;
    const int wid = tid >> 6, lane = tid & 63;
    const int quad = lane >> 4, l16 = lane & 15;
    const int qw = y * 64 + wid * 16;

    __shared__ __align__(16) unsigned short Ks[128 * 64];
    __shared__ __align__(16) unsigned char  Vs[64 * 128];
    __shared__ __align__(16) unsigned char  Ps[4][16 * 136];
    unsigned char* sp = Ps[wid];

    const unsigned short* Qp = Q + ((size_t)bh * SEQ + qw) * HDIM;
    bf16x8 aQ[2];
    aQ[0] = *(const bf16x8*)(Qp + l16 * HDIM + quad * 8);
    aQ[1] = *(const bf16x8*)(Qp + l16 * HDIM + 32 + quad * 8);

    int kql[4], vql[2];
#pragma unroll
    for (int j = 0; j < 4; j++) {
        int ck = (wid * 4 + j) * 64 + lane;
        int key = ck >> 3, ch = ck & 7;
        kql[j] = key * HDIM + ((ch ^ ((key >> 3) & 7)) * 8);
    }
#pragma unroll
    for (int j = 0; j < 2; j++) {
        int cv = j * 256 + wid * 64 + lane;
        int d = cv >> 3, ch = cv & 7;
        vql[j] = d * SEQ + ((ch ^ (d & 7)) * 16);
    }
    const unsigned short* Kb = Km + (size_t)bh * SEQ * HDIM;
    const unsigned char*  Vb = Vt + (size_t)bh * HDIM * SEQ;
    const float* Mbase = mask + (size_t)b * SEQ * SEQ
                       + (size_t)(qw + quad * 4) * SEQ + 8 * l16;

    f32x4 o[4] = {};
    f32x4 osum = {};
    const int SC1 = 0x7F7F7F7F;              // e8m0 unit scales
    i32x8 ONES8;                             // 32 x e4m3(1.0)
#pragma unroll
    for (int j = 0; j < 8; j++) ONES8[j] = 0x38383838;

    for (int key0 = 0; key0 < SEQ; key0 += 128) {
        // ---- mask preload: 8 fp32 per row per lane ----
        float mreg[4][8];
        const float* mb = Mbase + key0;
#pragma unroll
        for (int r = 0; r < 4; r++) {
            float4 u0 = *(const float4*)(mb + r * SEQ);
            float4 u1 = *(const float4*)(mb + r * SEQ + 4);
            mreg[r][0] = u0.x; mreg[r][1] = u0.y; mreg[r][2] = u0.z; mreg[r][3] = u0.w;
            mreg[r][4] = u1.x; mreg[r][5] = u1.y; mreg[r][6] = u1.z; mreg[r][7] = u1.w;
        }
        // ---- stage K (bf16) and V (e4m3) ----
        const unsigned short* Kg = Kb + (size_t)key0 * HDIM;
        const unsigned char*  Vg = Vb + key0;
#pragma unroll
        for (int j = 0; j < 4; j++)
            gl_lds16(Kg + kql[j], &Ks[(wid * 4 + j) * 512]);
#pragma unroll
        for (int j = 0; j < 2; j++)
            gl_lds16(Vg + vql[j], &Vs[(j * 256 + wid * 64) * 16]);
        __syncthreads();

        // ---- S = Q K^T (Q pre-scaled) ----
        f32x4 s[8];
        __builtin_amdgcn_s_setprio(1);
#pragma unroll
        for (int nt = 0; nt < 8; nt++) {
            const unsigned short* kp = &Ks[(8 * l16 + nt) * 64];
            bf16x8 b0 = *(const bf16x8*)&kp[(quad ^ (l16 & 7)) * 8];
            bf16x8 b1 = *(const bf16x8*)&kp[((4 + quad) ^ (l16 & 7)) * 8];
            f32x4 t = {};
            t = __builtin_amdgcn_mfma_f32_16x16x32_bf16(aQ[0], b0, t, 0, 0, 0);
            t = __builtin_amdgcn_mfma_f32_16x16x32_bf16(aQ[1], b1, t, 0, 0, 0);
            s[nt] = t;
        }
        __builtin_amdgcn_s_setprio(0);

        // ---- softmax numerators -> fp8 P in wave-private LDS ----
#pragma unroll
        for (int r = 0; r < 4; r++) {
            float e[8];
#pragma unroll
            for (int nt = 0; nt < 8; nt++)
                e[nt] = exp2f(fmaf(mreg[r][nt], L2E, s[nt][r]));
            unsigned int d0 = __builtin_amdgcn_cvt_pk_fp8_f32(e[0], e[1], 0, false);
            d0 = __builtin_amdgcn_cvt_pk_fp8_f32(e[2], e[3], d0, true);
            unsigned int d1 = __builtin_amdgcn_cvt_pk_fp8_f32(e[4], e[5], 0, false);
            d1 = __builtin_amdgcn_cvt_pk_fp8_f32(e[6], e[7], d1, true);
            int prow = quad * 4 + r;
            uint2 pv; pv.x = d0; pv.y = d1;
            *(uint2*)&sp[prow * 136 + ((l16 ^ (prow & 7)) * 8)] = pv;
        }
        __builtin_amdgcn_wave_barrier();

        // ---- O += P V ; denominator += P * ones (MX fp8 K=128) ----
        i32x8 aP;
        {
            const int sw = l16 & 7;
            union { long l[4]; i32x8 v; } u;
#pragma unroll
            for (int j = 0; j < 4; j++)
                u.l[j] = *(const long*)&sp[l16 * 136 + (((quad * 4 + j) ^ sw) * 8)];
            aP = u.v;
        }
        __builtin_amdgcn_s_setprio(1);
        osum = __builtin_amdgcn_mfma_scale_f32_16x16x128_f8f6f4(
            aP, ONES8, osum, 0, 0, 0, SC1, 0, SC1);
#pragma unroll
        for (int dt = 0; dt < 4; dt++) {
            const unsigned char* vp = &Vs[(dt * 16 + l16) * 128];
            const int c0 = ((quad * 2) ^ (l16 & 7)) * 16;
            i32x8 bv = ld_frag32(vp, c0, c0 ^ 16);
            o[dt] = __builtin_amdgcn_mfma_scale_f32_16x16x128_f8f6f4(
                aP, bv, o[dt], 0, 0, 0, SC1, 0, SC1);
        }
        __builtin_amdgcn_s_setprio(0);
        __syncthreads();
    }

#pragma unroll
    for (int r = 0; r < 4; r++) {
        float inv = 1.0f / osum[r];
#pragma unroll
        for (int dt = 0; dt < 4; dt++)
            O[(size_t)(b * SEQ + qw + quad * 4 + r) * DIMC + h * HDIM + dt * 16 + l16] =
                f2e4m3(o[dt][r] * inv);
    }
}

// ---------------------------------------------------------------------------
extern "C" void kernel_launch(void* const* d_in, const int* in_sizes, int n_in,
                              void* d_out, int out_size, void* d_ws, size_t ws_size,
                              hipStream_t stream) {
    const float* x_pre = (const float*)d_in[0];
    const float* x_post= (const float*)d_in[1];
    const float* mask  = (const float*)d_in[2];
    const float* ln1g  = (const float*)d_in[3];
    const float* ln1b  = (const float*)d_in[4];
    const float* Wq    = (const float*)d_in[5];
    const float* bq    = (const float*)d_in[6];
    const float* Wk    = (const float*)d_in[7];
    const float* bk    = (const float*)d_in[8];
    const float* Wv    = (const float*)d_in[9];
    const float* bv    = (const float*)d_in[10];
    const float* Wo    = (const float*)d_in[11];
    const float* bo    = (const float*)d_in[12];
    const float* ln2g  = (const float*)d_in[13];
    const float* ln2b  = (const float*)d_in[14];
    const float* W1    = (const float*)d_in[15];
    const float* b1    = (const float*)d_in[16];
    const float* W2    = (const float*)d_in[17];
    const float* b2    = (const float*)d_in[18];
    const float* g1    = (const float*)d_in[19];
    const float* g2    = (const float*)d_in[20];
    float* out = (float*)d_out;

    char* p = (char*)d_ws;
    float* xf  = (float*)p;                  p += (size_t)MROWS * DIMC * 4;
    float* x2f = (float*)p;                  p += (size_t)MROWS * DIMC * 4;
    unsigned char* h8  = (unsigned char*)p;  p += (size_t)MROWS * DIMC;
    unsigned char* O8  = (unsigned char*)p;  p += (size_t)MROWS * DIMC;
    unsigned char* G8  = (unsigned char*)p;  p += (size_t)MROWS * HIDDEN;
    unsigned short* Qb = (unsigned short*)p; p += (size_t)MROWS * DIMC * 2;
    unsigned short* Kb = (unsigned short*)p; p += (size_t)MROWS * DIMC * 2;
    unsigned char* V8  = (unsigned char*)p;  p += (size_t)MROWS * DIMC;
    unsigned char* Wq8 = (unsigned char*)p;  p += (size_t)DIMC * DIMC;
    unsigned char* Wk8 = (unsigned char*)p;  p += (size_t)DIMC * DIMC;
    unsigned char* Wv8 = (unsigned char*)p;  p += (size_t)DIMC * DIMC;
    unsigned char* Wo8 = (unsigned char*)p;  p += (size_t)DIMC * DIMC;
    unsigned char* W18 = (unsigned char*)p;  p += (size_t)DIMC * HIDDEN;
    unsigned char* W28 = (unsigned char*)p;  p += (size_t)DIMC * HIDDEN;

    dim3 tb(32, 8);
    tcvt_all<<<6912, tb, 0, stream>>>(Wq, Wk, Wv, Wo, W1, W2,
                                      Wq8, Wk8, Wv8, Wo8, W18, W28);

    ln_k<<<MROWS, 256, 0, stream>>>(x_pre, x_post, ln1g, ln1b, xf, h8);

    gemm_k<0, 128><<<dim3(6, 64, 3), 256, 0, stream>>>(h8, Wq8, Wk8, Wv8,
        bq, bk, bv, nullptr, nullptr, nullptr, Qb, Kb, nullptr, V8, DIMC, DIMC);

    attn_k<<<dim3(96, 16), 256, 0, stream>>>(Qb, Kb, V8, mask, O8);

    gemm_k<1, 64><<<dim3(6, 128), 256, 0, stream>>>(O8, Wo8, nullptr, nullptr,
        bo, nullptr, nullptr, xf, g1, x2f, nullptr, nullptr, nullptr, nullptr, DIMC, DIMC);

    ln_k<<<MROWS, 256, 0, stream>>>(x2f, nullptr, ln2g, ln2b, nullptr, h8);

    gemm_k<2, 128><<<dim3(24, 64), 256, 0, stream>>>(h8, W18, nullptr, nullptr,
        b1, nullptr, nullptr, nullptr, nullptr, nullptr, nullptr, nullptr, nullptr,
        G8, DIMC, HIDDEN);

    gemm_k<3, 64><<<dim3(6, 128), 256, 0, stream>>>(G8, W28, nullptr, nullptr,
        b2, nullptr, nullptr, x2f, g2, out, nullptr, nullptr, nullptr, nullptr,
        HIDDEN, DIMC);

    (void)in_sizes; (void)n_in; (void)out_size; (void)ws_size;
}